// Round 1
// baseline (160.977 us; speedup 1.0000x reference)
//
#include <hip/hip_runtime.h>

// ---------------------------------------------------------------------------
// AttentionHead: q=k_proj=v_proj = X @ Wq^T + bq (source bug: same proj for all),
// out = softmax(q k^T / 16) v.   B=4, S=4096, D=256, fp32 I/O.
// Pipeline: [proj GEMM -> bf16 Q,K,VT in ws] -> [flash attn, KV split 2] -> [merge]
// ---------------------------------------------------------------------------

typedef __attribute__((ext_vector_type(4)))  float    f32x4;
typedef __attribute__((ext_vector_type(16))) float    f32x16;
typedef __attribute__((ext_vector_type(8)))  short    s16x8;
typedef __attribute__((ext_vector_type(2)))  unsigned u32x2;

#define AS_GLB const __attribute__((address_space(1))) unsigned
#define AS_LDS __attribute__((address_space(3))) unsigned

static constexpr float CEXP = 0.09016844f;  // 1/(16*ln2): exp(x/16) == exp2(x*CEXP)

// workspace layout (bytes)
static constexpr size_t QBF_OFF = 0;                 // Q bf16 [B*S][256]            8 MB
static constexpr size_t KBF_OFF = 8ull  << 20;       // K bf16 [B*S][256]            8 MB
static constexpr size_t VTB_OFF = 16ull << 20;       // VT bf16 [B][256][4096]       8 MB
static constexpr size_t OT_OFF  = 24ull << 20;       // O^T partial f32 [2][B][256][4096] 32 MB
static constexpr size_t MS_OFF  = 56ull << 20;       // m f32 [2][B][4096]
static constexpr size_t LS_OFF  = MS_OFF + (128ull << 10);

__device__ __forceinline__ unsigned bf16_rne(float f) {
  union { float f; unsigned u; } v; v.f = f;
  return (v.u + 0x7FFFu + ((v.u >> 16) & 1u)) >> 16;
}
__device__ __forceinline__ unsigned pkbf16(float a, float b) {
  return bf16_rne(a) | (bf16_rne(b) << 16);
}

// ---------------------------------------------------------------------------
// Projection GEMM: C[m][n] = sum_k A[m][k] * Wq[n][k] + bq[n]
// A = concat(query,key,value) rows (3*16384), K=N=256.  128x128 tiles, BK=64.
// tensor 0 -> Q row-major bf16; 1 -> K row-major; 2 -> VT (transposed).
// ---------------------------------------------------------------------------
__global__ __launch_bounds__(256, 2) void proj_kernel(
    const float* __restrict__ Xq, const float* __restrict__ Xk,
    const float* __restrict__ Xv, const float* __restrict__ Wq,
    const float* __restrict__ bq, char* __restrict__ ws)
{
  __shared__ char plds[32768];  // As [128][128B swz] @0 ; Ws [128][128B swz] @16384
  const int tid = threadIdx.x;
  const int lane = tid & 63, w = tid >> 6;
  const int wr = w >> 1, wc = w & 1;
  const int l15 = lane & 15, l4 = (lane >> 4) & 3;

  const int mt = blockIdx.x;          // 0..383
  const int tensor = mt >> 7;         // 128 blocks per tensor
  const int r0 = (mt & 127) << 7;     // row base within tensor
  const int n0 = blockIdx.y << 7;     // 0 or 128
  const float* A = (tensor == 0) ? Xq : (tensor == 1 ? Xk : Xv);

  f32x4 acc[4][4];
#pragma unroll
  for (int i = 0; i < 4; ++i)
#pragma unroll
    for (int j = 0; j < 4; ++j) { acc[i][j][0]=0.f; acc[i][j][1]=0.f; acc[i][j][2]=0.f; acc[i][j][3]=0.f; }

  for (int kt = 0; kt < 4; ++kt) {
    const int k0 = kt << 6;
    // stage A and W tiles: f32 -> bf16, 16B-granule XOR swizzle on 128B rows
#pragma unroll
    for (int j = 0; j < 8; ++j) {
      int c = j * 256 + tid;
      int row = c >> 4, col4 = c & 15;            // 16 f32x4-chunks per 64-elem row
      f32x4 av = *(const f32x4*)(A + (size_t)(r0 + row) * 256 + k0 + col4 * 4);
      u32x2 pa; pa[0] = pkbf16(av[0], av[1]); pa[1] = pkbf16(av[2], av[3]);
      int off = row * 128 + ((col4 * 8) ^ ((row & 7) << 4));
      *(u32x2*)(plds + off) = pa;
      f32x4 wv = *(const f32x4*)(Wq + (size_t)(n0 + row) * 256 + k0 + col4 * 4);
      u32x2 pw; pw[0] = pkbf16(wv[0], wv[1]); pw[1] = pkbf16(wv[2], wv[3]);
      *(u32x2*)(plds + 16384 + off) = pw;
    }
    __syncthreads();
#pragma unroll
    for (int ks = 0; ks < 2; ++ks) {
      s16x8 af[4], wf[4];
#pragma unroll
      for (int mi = 0; mi < 4; ++mi) {
        int row = wr * 64 + mi * 16 + l15;
        af[mi] = *(const s16x8*)(plds + row * 128 + ((ks * 64 + l4 * 16) ^ ((row & 7) << 4)));
      }
#pragma unroll
      for (int ni = 0; ni < 4; ++ni) {
        int row = wc * 64 + ni * 16 + l15;
        wf[ni] = *(const s16x8*)(plds + 16384 + row * 128 + ((ks * 64 + l4 * 16) ^ ((row & 7) << 4)));
      }
#pragma unroll
      for (int mi = 0; mi < 4; ++mi)
#pragma unroll
        for (int ni = 0; ni < 4; ++ni)
          acc[mi][ni] = __builtin_amdgcn_mfma_f32_16x16x32_bf16(af[mi], wf[ni], acc[mi][ni], 0, 0, 0);
    }
    __syncthreads();
  }

  unsigned short* Qb = (unsigned short*)(ws + QBF_OFF);
  unsigned short* Kb = (unsigned short*)(ws + KBF_OFF);
  char*           Vt = ws + VTB_OFF;
#pragma unroll
  for (int ni = 0; ni < 4; ++ni) {
    int gn = n0 + wc * 64 + ni * 16 + l15;
    float bias = bq[gn];
#pragma unroll
    for (int mi = 0; mi < 4; ++mi) {
      int mrow = r0 + wr * 64 + mi * 16 + l4 * 4;   // 4 consecutive rows (j)
      if (tensor < 2) {
        unsigned short* dst = tensor ? Kb : Qb;
#pragma unroll
        for (int j = 0; j < 4; ++j)
          dst[(size_t)(mrow + j) * 256 + gn] = (unsigned short)bf16_rne(acc[mi][ni][j] + bias);
      } else {
        int b = mrow >> 12, s = mrow & 4095;
        u32x2 pv;
        pv[0] = pkbf16(acc[mi][ni][0] + bias, acc[mi][ni][1] + bias);
        pv[1] = pkbf16(acc[mi][ni][2] + bias, acc[mi][ni][3] + bias);
        *(u32x2*)(Vt + ((size_t)(b * 256 + gn) * 4096 + s) * 2) = pv;
      }
    }
  }
}

// ---------------------------------------------------------------------------
// Flash attention (swapped-QK, 32x32x16 MFMA). 4 waves x 32 q-rows = 128 q/block.
// KVBLK=32 double-buffered (64 KiB LDS), KV split 2-way across blocks.
// grid = 256: bid -> b = bid>>6, qblk = (bid>>1)&31, sp = bid&1.
// ---------------------------------------------------------------------------
__global__ __launch_bounds__(256, 1) void flash_kernel(char* __restrict__ ws)
{
  __shared__ char lds[65536];  // K0@0 K1@16K V0@32K V1@48K
  const int tid = threadIdx.x;
  const int lane = tid & 63, w = tid >> 6;
  const int l31 = lane & 31, h = lane >> 5;

  const int bid = blockIdx.x;
  const int b    = bid >> 6;
  const int qblk = (bid >> 1) & 31;
  const int sp   = bid & 1;
  const int q0w  = qblk * 128 + w * 32;
  const int kvbase = sp * 2048;

  const char* Kgb = ws + KBF_OFF + (size_t)b * 4096 * 512;  // key rows, 512B each
  const char* Vgb = ws + VTB_OFF + (size_t)b * 256 * 8192;  // VT rows (d), 8KB each

  // Q fragments: lane covers q = q0w + l31; slab i holds d = 16i + 8h + j
  s16x8 qf[16];
  {
    const char* qrow = ws + QBF_OFF + (size_t)((b << 12) + q0w + l31) * 512 + h * 16;
#pragma unroll
    for (int i = 0; i < 16; ++i) qf[i] = *(const s16x8*)(qrow + i * 32);
  }

  f32x16 O[8];
#pragma unroll
  for (int t8 = 0; t8 < 8; ++t8)
#pragma unroll
    for (int r = 0; r < 16; ++r) O[t8][r] = 0.f;

  float m_run = -1e30f, l_run = 0.f;

  auto STAGE = [&](int buf, int t) {
    const int kv0 = kvbase + t * 32;
#pragma unroll
    for (int i = 0; i < 4; ++i) {
      unsigned off = ((unsigned)(w * 4 + i) << 10) + ((unsigned)lane << 4);
      {  // K tile [32 keys][512B], swizzle byte ^= (key&7)<<4
        unsigned row = off >> 9, col = off & 511u;
        const char* src = Kgb + (size_t)(kv0 + row) * 512 + (col ^ ((row & 7) << 4));
        __builtin_amdgcn_global_load_lds((AS_GLB*)src,
            (AS_LDS*)(lds + buf * 16384 + ((w * 4 + i) << 10)), 16, 0, 0);
      }
      {  // VT tile [256 d][64B], swizzle byte ^= (d&3)<<4
        unsigned row = off >> 6, col = off & 63u;
        const char* src = Vgb + (size_t)row * 8192 + (size_t)kv0 * 2 + (col ^ ((row & 3) << 4));
        __builtin_amdgcn_global_load_lds((AS_GLB*)src,
            (AS_LDS*)(lds + 32768 + buf * 16384 + ((w * 4 + i) << 10)), 16, 0, 0);
      }
    }
  };

  auto COMPUTE = [&](int buf) {
    const char* kb = lds + buf * 16384;
    const char* vb = lds + 32768 + buf * 16384;
    // QK^T swapped: D[key][q], q = l31, key = (r&3)+8*(r>>2)+4h
    f32x16 p;
#pragma unroll
    for (int r = 0; r < 16; ++r) p[r] = 0.f;
    {
      const unsigned kswz = (unsigned)((l31 & 7) << 4);
      const char* krow = kb + (l31 << 9);
#pragma unroll
      for (int i = 0; i < 16; ++i) {
        s16x8 kf = *(const s16x8*)(krow + (((unsigned)(i * 32 + h * 16)) ^ kswz));
        p = __builtin_amdgcn_mfma_f32_32x32x16_bf16(kf, qf[i], p, 0, 0, 0);
      }
    }
    // online softmax (scores in raw units; /16 folded into exp slope CEXP)
    float pm = p[0];
#pragma unroll
    for (int r = 1; r < 16; ++r) pm = fmaxf(pm, p[r]);
    pm = fmaxf(pm, __shfl_xor(pm, 32, 64));
    if (__any(pm > m_run + 32.0f)) {  // T13 defer-max: rescale only on real growth
      float mnew = fmaxf(m_run, pm);
      float alpha = __builtin_exp2f((m_run - mnew) * CEXP);
      m_run = mnew;
      l_run *= alpha;
#pragma unroll
      for (int r = 0; r < 16; ++r) {
        float av = __shfl(alpha, (r & 3) + 8 * (r >> 2) + 4 * h, 64);
#pragma unroll
        for (int t8 = 0; t8 < 8; ++t8) O[t8][r] *= av;
      }
    }
    float sig = 0.f;
#pragma unroll
    for (int r = 0; r < 16; ++r) {
      float e = __builtin_exp2f((p[r] - m_run) * CEXP);
      p[r] = e; sig += e;
    }
    sig += __shfl_xor(sig, 32, 64);
    l_run += sig;
    // P -> bf16 A-fragments (T12: cvt_pk pairs + permlane32_swap)
    unsigned a0 = pkbf16(p[0], p[1]),   a1 = pkbf16(p[2], p[3]);
    unsigned b0 = pkbf16(p[4], p[5]),   b1 = pkbf16(p[6], p[7]);
    unsigned c0 = pkbf16(p[8], p[9]),   c1 = pkbf16(p[10], p[11]);
    unsigned d0 = pkbf16(p[12], p[13]), d1 = pkbf16(p[14], p[15]);
    asm("v_permlane32_swap_b32 %0, %1" : "+v"(a0), "+v"(b0));
    asm("v_permlane32_swap_b32 %0, %1" : "+v"(a1), "+v"(b1));
    asm("v_permlane32_swap_b32 %0, %1" : "+v"(c0), "+v"(d0));
    asm("v_permlane32_swap_b32 %0, %1" : "+v"(c1), "+v"(d1));
    union { s16x8 v; unsigned u[4]; } pa0, pa1;
    pa0.u[0] = a0; pa0.u[1] = a1; pa0.u[2] = b0; pa0.u[3] = b1;  // k 0..15
    pa1.u[0] = c0; pa1.u[1] = c1; pa1.u[2] = d0; pa1.u[3] = d1;  // k 16..31
    // PV: O[q][d] += P[q][k] V[k][d], B-frag from VT rows
    const unsigned vswz = (unsigned)((l31 & 3) << 4);
#pragma unroll
    for (int t8 = 0; t8 < 8; ++t8) {
      const char* vrow = vb + ((t8 * 32 + l31) << 6);
      s16x8 v0 = *(const s16x8*)(vrow + (((unsigned)(h * 16)) ^ vswz));
      O[t8] = __builtin_amdgcn_mfma_f32_32x32x16_bf16(pa0.v, v0, O[t8], 0, 0, 0);
      s16x8 v1 = *(const s16x8*)(vrow + (((unsigned)(32 + h * 16)) ^ vswz));
      O[t8] = __builtin_amdgcn_mfma_f32_32x32x16_bf16(pa1.v, v1, O[t8], 0, 0, 0);
    }
  };

  STAGE(0, 0);
  __syncthreads();
  for (int t = 0; t < 64; t += 2) {
    STAGE(1, t + 1);
    COMPUTE(0);
    __syncthreads();
    if (t + 2 < 64) STAGE(0, t + 2);
    COMPUTE(1);
    __syncthreads();
  }

  // store partial O^T [sp][b][d][s] + per-q stats (unnormalized; merge finishes)
  float* OT = (float*)(ws + OT_OFF);
#pragma unroll
  for (int t8 = 0; t8 < 8; ++t8) {
    int d = t8 * 32 + l31;
    float* rowp = OT + ((size_t)((sp * 4 + b) * 256 + d) << 12);
#pragma unroll
    for (int g = 0; g < 4; ++g) {
      f32x4 vv;
      vv[0] = O[t8][g * 4 + 0]; vv[1] = O[t8][g * 4 + 1];
      vv[2] = O[t8][g * 4 + 2]; vv[3] = O[t8][g * 4 + 3];
      *(f32x4*)(rowp + q0w + g * 8 + h * 4) = vv;
    }
  }
  if (lane < 32) {
    int idx = ((sp * 4 + b) << 12) + q0w + l31;
    ((float*)(ws + MS_OFF))[idx] = m_run;
    ((float*)(ws + LS_OFF))[idx] = l_run;
  }
}

// ---------------------------------------------------------------------------
// Merge 2 KV-splits + normalize: out[b][s][d] (f32, coalesced over d).
// ---------------------------------------------------------------------------
__global__ __launch_bounds__(256) void merge_kernel(const char* __restrict__ ws,
                                                    float* __restrict__ out)
{
  const int t = threadIdx.x;            // d
  const int b = blockIdx.x;
  const int s0 = blockIdx.y << 6;
  const float* OT = (const float*)(ws + OT_OFF);
  const float* Ms = (const float*)(ws + MS_OFF);
  const float* Ls = (const float*)(ws + LS_OFF);
  const float* o0 = OT + ((size_t)(b * 256 + t) << 12);
  const float* o1 = OT + ((size_t)((4 + b) * 256 + t) << 12);
  for (int si4 = 0; si4 < 16; ++si4) {
    int s = s0 + si4 * 4;
    f32x4 a = *(const f32x4*)(o0 + s);
    f32x4 c = *(const f32x4*)(o1 + s);
#pragma unroll
    for (int j = 0; j < 4; ++j) {
      int sj = s + j;
      float m0 = Ms[(b << 12) + sj], m1 = Ms[((4 + b) << 12) + sj];
      float l0 = Ls[(b << 12) + sj], l1 = Ls[((4 + b) << 12) + sj];
      float M = fmaxf(m0, m1);
      float w0 = __builtin_exp2f((m0 - M) * CEXP);
      float w1 = __builtin_exp2f((m1 - M) * CEXP);
      float rd = 1.0f / (w0 * l0 + w1 * l1);
      out[((size_t)(b << 12) + sj) * 256 + t] = (w0 * a[j] + w1 * c[j]) * rd;
    }
  }
}

extern "C" void kernel_launch(void* const* d_in, const int* in_sizes, int n_in,
                              void* d_out, int out_size, void* d_ws, size_t ws_size,
                              hipStream_t stream) {
  const float* q  = (const float*)d_in[0];
  const float* k  = (const float*)d_in[1];
  const float* v  = (const float*)d_in[2];
  const float* Wq = (const float*)d_in[3];
  const float* bq = (const float*)d_in[4];
  char* ws = (char*)d_ws;
  float* out = (float*)d_out;
  hipLaunchKernelGGL(proj_kernel, dim3(384, 2), dim3(256), 0, stream, q, k, v, Wq, bq, ws);
  hipLaunchKernelGGL(flash_kernel, dim3(256), dim3(256), 0, stream, ws);
  hipLaunchKernelGGL(merge_kernel, dim3(4, 64), dim3(256), 0, stream, ws, out);
}